// Round 15
// baseline (278.426 us; speedup 1.0000x reference)
//
#include <hip/hip_runtime.h>
#include <hip/hip_bf16.h>

// LSTM_Actor v13: v10 skeleton (best: 213us) minus provable work.
//  (1) prescaled weights (-log2e i/f/o, +2log2e g): activation = rcp(1+exp2(y))
//  (2) x fully out of LDS: each lane builds its exact X0/X1 MFMA fragment from
//      4 global float4 loads per 2 steps (row lr>>1, plane t+(lr&1), k=lg*8).
//      L1 serves the 8x cross-wave duplication; LDS act buffer shrinks to 4KB
//      (h only). LDS pipe ~-120cyc/CU/step; VALU -~40cyc/SIMD.
// Everything else IS v10: 256 blocks x 512 thr (8 waves), 8 rows/block,
// x-pair M-packing (even C-rows = t, odd = t+1), one x-pass per 2 steps with
// xC carried across the barrier, separate H accs (NO chaining - v11b lesson),
// DPP row_ror:8 exchange, one lgkm-only barrier/step, proj round-robin.

#define TT 512
#define BB 2048
#define DD 64
#define AA 16

typedef short bf16x8 __attribute__((ext_vector_type(8)));
typedef float f32x4 __attribute__((ext_vector_type(4)));

#define MFMA16(a, b, c) __builtin_amdgcn_mfma_f32_16x16x32_bf16((a), (b), (c), 0, 0, 0)

#if defined(__has_builtin)
#  if __has_builtin(__builtin_amdgcn_exp2f)
#    define EXP2F(x) __builtin_amdgcn_exp2f(x)
#  else
#    define EXP2F(x) exp2f(x)
#  endif
#  if __has_builtin(__builtin_amdgcn_rcpf)
#    define RCPF(x) __builtin_amdgcn_rcpf(x)
#  else
#    define RCPF(x) (1.0f/(x))
#  endif
#else
#  define EXP2F(x) exp2f(x)
#  define RCPF(x) (1.0f/(x))
#endif

#define GS_I (-1.4426950408889634f)   // sigmoid pre-scale
#define GS_G (2.8853900817779268f)    // tanh pre-scale

__device__ __forceinline__ unsigned short bfu(float f) {
  union { __hip_bfloat16 b; unsigned short u; } cv;
  cv.b = __float2bfloat16(f);
  return cv.u;
}
__device__ __forceinline__ unsigned cvtpk2(float a, float b) {  // [b|a] bf16 RNE
  union { __hip_bfloat162 b2; unsigned u; } cv;
  cv.b2 = __float22bfloat162_rn(make_float2(a, b));
  return cv.u;
}
// xor-by-8 across lanes via DPP row_ror:8 (HW-validated v9-v12).
__device__ __forceinline__ float dpp_xor8(float v) {
  int i = __builtin_bit_cast(int, v);
  int r = __builtin_amdgcn_update_dpp(i, i, 0x128, 0xF, 0xF, true);
  return __builtin_bit_cast(float, r);
}
// 16B-slot swizzle within a 128B region (v10's variant).
__device__ __forceinline__ int swz(int row, int slot) {
  return (slot ^ (row & 7) ^ ((row & 8) >> 1)) & 7;
}
// lgkm-only barrier: LDS writes visible; global loads stay in flight.
__device__ __forceinline__ void block_sync_lds() {
  __builtin_amdgcn_sched_barrier(0);
  asm volatile("s_waitcnt lgkmcnt(0)" ::: "memory");
  __builtin_amdgcn_s_barrier();
  __builtin_amdgcn_sched_barrier(0);
}

__global__ __launch_bounds__(512, 2)
void lstm_actor_v13(const float* __restrict__ x,
                    const float* __restrict__ W_ih,
                    const float* __restrict__ W_hh,
                    const float* __restrict__ b_ih,
                    const float* __restrict__ b_hh,
                    const float* __restrict__ W_out,
                    const float* __restrict__ b_out,
                    float* __restrict__ out) {
  // h-only LDS: 16 A-rows x (par0 128B | par1 128B) = 4 KB.
  __shared__ __align__(16) unsigned short act[16 * 128];
  char* actb = (char*)act;

  const int tid  = threadIdx.x;
  const int lane = tid & 63;
  const int w    = tid >> 6;       // wave 0..7: j-slice j0 = 8w
  const int lr   = lane & 15;
  const int lg   = lane >> 4;
  const int qq   = lr >> 3;        // 0/1: quadrant within tile pair
  const int jj   = lr & 7;
  const int r0   = blockIdx.x * 8;
  const int j0   = w * 8;

  const f32x4 Z = {0.f, 0.f, 0.f, 0.f};

  // ---- weights (bf16, PRE-SCALED): 2 packed N-tiles x 2 k-frags ----
  // gate = nt*2+qq: 0=i,1=f,2=g,3=o. GS_G for g (nt==1,qq==0), else GS_I.
  bf16x8 Bih[2][2], Bhh[2][2];
  float biasv[2];
#pragma unroll
  for (int nt = 0; nt < 2; ++nt) {
    const int g = (nt * 2 + qq) * 64 + j0 + jj;
    const float sc = (nt == 1 && qq == 0) ? GS_G : GS_I;
    biasv[nt] = sc * (b_ih[g] + b_hh[g]);
#pragma unroll
    for (int kt = 0; kt < 2; ++kt) {
      const float* si = W_ih + g * 64 + kt * 32 + lg * 8;
      const float* sh = W_hh + g * 64 + kt * 32 + lg * 8;
      bf16x8 vi, vh;
#pragma unroll
      for (int u = 0; u < 8; ++u) {
        vi[u] = (short)bfu(sc * si[u]);
        vh[u] = (short)bfu(sc * sh[u]);
      }
      Bih[nt][kt] = vi; Bhh[nt][kt] = vh;
    }
  }

  // ---- projection weights (unscaled, all waves) ----
  bf16x8 pb[2];
  const float bo = b_out[lr];
#pragma unroll
  for (int kt = 0; kt < 2; ++kt) {
    const float* src = W_out + lr * 64 + kt * 32 + lg * 8;
    bf16x8 vh;
#pragma unroll
    for (int u = 0; u < 8; ++u) vh[u] = (short)bfu(src[u]);
    pb[kt] = vh;
  }

  // ---- h LDS geometry (A-row 2q = h[row q]; odd A-rows stay zero) ----
  int aoffH[2];
#pragma unroll
  for (int kt = 0; kt < 2; ++kt)
    aoffH[kt] = lr * 256 + swz(lr, kt * 4 + lg) * 16;
  const int hrow = 2 * lg + qq;            // real row this lane owns
  const int hj   = j0 + jj;
  const int hWb  = (2 * hrow) * 256 + swz(2 * hrow, hj >> 3) * 16 + ((hj * 2) & 15);

  // ---- x direct-from-global geometry ----
  // lane's X-frag: plane t + (lr&1), row lr>>1, k = kt*32 + lg*8 + (0..7)
  const size_t XS = (size_t)BB * DD;
  const float* xbase = x + ((size_t)(lr & 1) * BB + r0 + (lr >> 1)) * DD + lg * 8;

  // ---- zero h LDS (h(-1)=0, both parities) ----
  for (int i = tid; i < 16 * 128 / 2; i += 512) ((unsigned*)act)[i] = 0u;

  // ---- prologue x loads: FA = iter0 (x(0),x(1)), FB = iter1 (x(2),x(3)) ----
  float4 FA0, FA1, FA2, FA3, FB0, FB1, FB2, FB3;
  FA0 = *(const float4*)(xbase);
  FA1 = *(const float4*)(xbase + 4);
  FA2 = *(const float4*)(xbase + 32);
  FA3 = *(const float4*)(xbase + 36);
  FB0 = *(const float4*)(xbase + 2 * XS);
  FB1 = *(const float4*)(xbase + 2 * XS + 4);
  FB2 = *(const float4*)(xbase + 2 * XS + 32);
  FB3 = *(const float4*)(xbase + 2 * XS + 36);

  float c_state = 0.0f;
  __syncthreads();

  // ---- gates + elementwise (prescaled) + h write ----
  auto gates_and_h = [&](float a0, float b0, float a1, float b1, int hwp) {
    // a0/b0 = rows 2lg/2lg+1 tile0; a1/b1 = tile1.
    const float rcv0 = dpp_xor8(qq ? a0 : b0);
    const float rcv1 = dpp_xor8(qq ? a1 : b1);
    const float iv_ = qq ? rcv0 : a0;
    const float fv_ = qq ? b0 : rcv0;
    const float gv_ = qq ? rcv1 : a1;
    const float ov_ = qq ? b1 : rcv1;
    const float iv = RCPF(1.0f + EXP2F(iv_));
    const float fv = RCPF(1.0f + EXP2F(fv_));
    const float gv = fmaf(-2.0f, RCPF(1.0f + EXP2F(gv_)), 1.0f);
    const float ov = RCPF(1.0f + EXP2F(ov_));
    c_state = fmaf(fv, c_state, iv * gv);
    const float tc = fmaf(-2.0f, RCPF(1.0f + EXP2F(GS_G * c_state)), 1.0f);
    *(unsigned short*)(actb + hWb + hwp) = bfu(ov * tc);
  };

  // ---- one iteration = steps t (par0->par1), t+1 (par1->par0) ----
  auto iter2 = [&](int t, float4& F0, float4& F1, float4& F2, float4& F3) {
    // build X frags from F (loaded 2 iterations ago), then reuse F for t+4
    bf16x8 X0, X1;
    {
      unsigned* u0 = (unsigned*)&X0; unsigned* u1 = (unsigned*)&X1;
      u0[0] = cvtpk2(F0.x, F0.y); u0[1] = cvtpk2(F0.z, F0.w);
      u0[2] = cvtpk2(F1.x, F1.y); u0[3] = cvtpk2(F1.z, F1.w);
      u1[0] = cvtpk2(F2.x, F2.y); u1[1] = cvtpk2(F2.z, F2.w);
      u1[2] = cvtpk2(F3.x, F3.y); u1[3] = cvtpk2(F3.z, F3.w);
    }
    if (t + 4 < TT) {
      const float* p = xbase + (size_t)(t + 4) * XS;
      F0 = *(const float4*)(p);
      F1 = *(const float4*)(p + 4);
      F2 = *(const float4*)(p + 32);
      F3 = *(const float4*)(p + 36);
    }

    // ---- step A: h par0 -> par1 ----
    {
      const bf16x8 A2 = *(const bf16x8*)(actb + aoffH[0]);
      const bf16x8 A3 = *(const bf16x8*)(actb + aoffH[1]);
      // x-pass (bias folded): xC[0]/[2] = step t rows, [1]/[3] = step t+1
      f32x4 xCa = {biasv[0], biasv[0], biasv[0], biasv[0]};
      f32x4 xCb = {biasv[1], biasv[1], biasv[1], biasv[1]};
      xCa = MFMA16(X0, Bih[0][0], xCa); xCa = MFMA16(X1, Bih[0][1], xCa);
      xCb = MFMA16(X0, Bih[1][0], xCb); xCb = MFMA16(X1, Bih[1][1], xCb);
      f32x4 H0 = MFMA16(A2, Bhh[0][0], Z); H0 = MFMA16(A3, Bhh[0][1], H0);
      f32x4 H1 = MFMA16(A2, Bhh[1][0], Z); H1 = MFMA16(A3, Bhh[1][1], H1);

      const bool do_proj = (w == (t & 7)) && (t > 0);
      if (do_proj) {
        f32x4 pacc = MFMA16(A2, pb[0], Z);
        pacc = MFMA16(A3, pb[1], pacc);
        const size_t base = ((size_t)(t - 1) * BB + r0 + 2 * lg) * AA + lr;
        out[base]      = pacc[0] + bo;
        out[base + AA] = pacc[2] + bo;
      }
      gates_and_h(H0[0] + xCa[0], H0[2] + xCa[2],
                  H1[0] + xCb[0], H1[2] + xCb[2], 128);
      block_sync_lds();

      // ---- step B: h par1 -> par0 (x from carried xC odd rows) ----
      const bf16x8 B2 = *(const bf16x8*)(actb + aoffH[0] + 128);
      const bf16x8 B3 = *(const bf16x8*)(actb + aoffH[1] + 128);
      f32x4 G0 = MFMA16(B2, Bhh[0][0], Z); G0 = MFMA16(B3, Bhh[0][1], G0);
      f32x4 G1 = MFMA16(B2, Bhh[1][0], Z); G1 = MFMA16(B3, Bhh[1][1], G1);

      if (w == ((t + 1) & 7)) {
        f32x4 pacc = MFMA16(B2, pb[0], Z);
        pacc = MFMA16(B3, pb[1], pacc);
        const size_t base = ((size_t)t * BB + r0 + 2 * lg) * AA + lr;
        out[base]      = pacc[0] + bo;
        out[base + AA] = pacc[2] + bo;
      }
      gates_and_h(G0[0] + xCa[1], G0[2] + xCa[3],
                  G1[0] + xCb[1], G1[2] + xCb[3], 0);
      block_sync_lds();
    }
  };

  for (int t = 0; t < TT; t += 4) {
    iter2(t,     FA0, FA1, FA2, FA3);
    iter2(t + 2, FB0, FB1, FB2, FB3);
  }

  // ---- epilogue: out[TT-1] from h(TT-1) (par0) ----
  if (w == (TT & 7)) {
    const bf16x8 A2 = *(const bf16x8*)(actb + aoffH[0]);
    const bf16x8 A3 = *(const bf16x8*)(actb + aoffH[1]);
    f32x4 pacc = MFMA16(A2, pb[0], Z);
    pacc = MFMA16(A3, pb[1], pacc);
    const size_t base = ((size_t)(TT - 1) * BB + r0 + 2 * lg) * AA + lr;
    out[base]      = pacc[0] + bo;
    out[base + AA] = pacc[2] + bo;
  }
}

extern "C" void kernel_launch(void* const* d_in, const int* in_sizes, int n_in,
                              void* d_out, int out_size, void* d_ws, size_t ws_size,
                              hipStream_t stream) {
  const float* x     = (const float*)d_in[0];
  const float* W_ih  = (const float*)d_in[1];
  const float* W_hh  = (const float*)d_in[2];
  const float* b_ih  = (const float*)d_in[3];
  const float* b_hh  = (const float*)d_in[4];
  const float* W_out = (const float*)d_in[5];
  const float* b_out = (const float*)d_in[6];
  float* out = (float*)d_out;

  lstm_actor_v13<<<dim3(BB / 8), dim3(512), 0, stream>>>(
      x, W_ih, W_hh, b_ih, b_hh, W_out, b_out, out);
}

// Round 16
// 180.663 us; speedup vs baseline: 1.5411x; 1.5411x over previous
//
#include <hip/hip_runtime.h>
#include <hip/hip_bf16.h>

// LSTM_Actor v14: v10 (best, 213us) + ONLY the two validated work deletions:
//  (1) prescaled weights (-log2e i/f/o, +2log2e g; bias prescaled): activation
//      = rcp(1+exp2(y)) with no leading mul  [numerics validated v11b/v13,
//      absmax 3.9e-3]
//  (2) 8-step full unroll (4 x iter2, literal proj-wave ids + literal x/h
//      parities): loop/parity/select arithmetic deleted, ds-write parity
//      folded to immediates, x prefetch regs renamed by unroll.
// EVERYTHING else is v10 verbatim: 256 blocks x 512 thr (8 waves), 8 rows/blk,
// x-pair M-packing (A-row 2q = x(t) row q, 2q+1 = x(t+1) row q; h at even
// A-rows, odd h rows zero), x staged via LDS (cvtpk b32/lane per 2 steps),
// SEPARATE H and xC accumulators (+4 adds; no chaining), DPP row_ror:8
// exchange, one lgkm-only barrier per step, proj round-robin w==t&7.

#define TT 512
#define BB 2048
#define DD 64
#define AA 16
#define ROWB 512   // per A-row: x par0 128 | x par1 128 | h par0 128 | h par1 128

typedef short bf16x8 __attribute__((ext_vector_type(8)));
typedef float f32x4 __attribute__((ext_vector_type(4)));

#define MFMA16(a, b, c) __builtin_amdgcn_mfma_f32_16x16x32_bf16((a), (b), (c), 0, 0, 0)

#if defined(__has_builtin)
#  if __has_builtin(__builtin_amdgcn_exp2f)
#    define EXP2F(x) __builtin_amdgcn_exp2f(x)
#  else
#    define EXP2F(x) exp2f(x)
#  endif
#  if __has_builtin(__builtin_amdgcn_rcpf)
#    define RCPF(x) __builtin_amdgcn_rcpf(x)
#  else
#    define RCPF(x) (1.0f/(x))
#  endif
#else
#  define EXP2F(x) exp2f(x)
#  define RCPF(x) (1.0f/(x))
#endif

#define GS_I (-1.4426950408889634f)   // sigmoid pre-scale
#define GS_G (2.8853900817779268f)    // tanh pre-scale

__device__ __forceinline__ unsigned short bfu(float f) {
  union { __hip_bfloat16 b; unsigned short u; } cv;
  cv.b = __float2bfloat16(f);
  return cv.u;
}
__device__ __forceinline__ unsigned cvtpk2(float a, float b) {  // [b|a] bf16 RNE
  union { __hip_bfloat162 b2; unsigned u; } cv;
  cv.b2 = __float22bfloat162_rn(make_float2(a, b));
  return cv.u;
}
// xor-by-8 across lanes via DPP row_ror:8 (HW-validated v9-v13).
__device__ __forceinline__ float dpp_xor8(float v) {
  int i = __builtin_bit_cast(int, v);
  int r = __builtin_amdgcn_update_dpp(i, i, 0x128, 0xF, 0xF, true);
  return __builtin_bit_cast(float, r);
}
// 16B-slot swizzle within a 128B region (v10's variant).
__device__ __forceinline__ int swz(int row, int slot) {
  return (slot ^ (row & 7) ^ ((row & 8) >> 1)) & 7;
}
// lgkm-only barrier: LDS writes visible; global loads stay in flight.
__device__ __forceinline__ void block_sync_lds() {
  __builtin_amdgcn_sched_barrier(0);
  asm volatile("s_waitcnt lgkmcnt(0)" ::: "memory");
  __builtin_amdgcn_s_barrier();
  __builtin_amdgcn_sched_barrier(0);
}

__global__ __launch_bounds__(512, 2)
void lstm_actor_v14(const float* __restrict__ x,
                    const float* __restrict__ W_ih,
                    const float* __restrict__ W_hh,
                    const float* __restrict__ b_ih,
                    const float* __restrict__ b_hh,
                    const float* __restrict__ W_out,
                    const float* __restrict__ b_out,
                    float* __restrict__ out) {
  __shared__ __align__(16) unsigned short act[16 * ROWB / 2];  // 8 KB
  char* actb = (char*)act;

  const int tid  = threadIdx.x;
  const int lane = tid & 63;
  const int w    = tid >> 6;       // wave 0..7: j-slice j0 = 8w
  const int lr   = lane & 15;
  const int lg   = lane >> 4;
  const int qq   = lr >> 3;        // 0/1: quadrant within tile pair
  const int jj   = lr & 7;
  const int r0   = blockIdx.x * 8;
  const int j0   = w * 8;

  const f32x4 Z = {0.f, 0.f, 0.f, 0.f};

  // ---- weights (bf16, PRE-SCALED): 2 packed N-tiles x 2 k-frags ----
  // gate = nt*2+qq: 0=i,1=f,2=g,3=o. GS_G for g (nt==1,qq==0), else GS_I.
  bf16x8 Bih[2][2], Bhh[2][2];
  float biasv[2];
#pragma unroll
  for (int nt = 0; nt < 2; ++nt) {
    const int g = (nt * 2 + qq) * 64 + j0 + jj;
    const float sc = (nt == 1 && qq == 0) ? GS_G : GS_I;
    biasv[nt] = sc * (b_ih[g] + b_hh[g]);
#pragma unroll
    for (int kt = 0; kt < 2; ++kt) {
      const float* si = W_ih + g * 64 + kt * 32 + lg * 8;
      const float* sh = W_hh + g * 64 + kt * 32 + lg * 8;
      bf16x8 vi, vh;
#pragma unroll
      for (int u = 0; u < 8; ++u) {
        vi[u] = (short)bfu(sc * si[u]);
        vh[u] = (short)bfu(sc * sh[u]);
      }
      Bih[nt][kt] = vi; Bhh[nt][kt] = vh;
    }
  }

  // ---- projection weights (unscaled, all waves) ----
  bf16x8 pb[2];
  const float bo = b_out[lr];
#pragma unroll
  for (int kt = 0; kt < 2; ++kt) {
    const float* src = W_out + lr * 64 + kt * 32 + lg * 8;
    bf16x8 vh;
#pragma unroll
    for (int u = 0; u < 8; ++u) vh[u] = (short)bfu(src[u]);
    pb[kt] = vh;
  }

  // ---- LDS geometry (v10) ----
  int aoffX[2], aoffH[2];
#pragma unroll
  for (int kt = 0; kt < 2; ++kt) {
    aoffX[kt] = lr * ROWB + swz(lr, kt * 4 + lg) * 16;
    aoffH[kt] = aoffX[kt] + 256;
  }
  const int hrow = 2 * lg + qq;
  const int hj   = j0 + jj;
  const int hWb  = (2 * hrow) * ROWB + 256 + swz(2 * hrow, hj >> 3) * 16 + ((hj * 2) & 15);
  const int xrow = 2 * w + (lane >> 5);
  const int xj   = 2 * (lane & 31);
  const int xWb  = xrow * ROWB + swz(xrow, xj >> 3) * 16 + ((2 * xj) & 15);

  // ---- zero LDS (odd-row h region stays zero forever; h(-1)=0) ----
  for (int i = tid; i < 16 * ROWB / 4; i += 512) ((unsigned*)act)[i] = 0u;
  __syncthreads();

  // ---- stage x(0)/x(1) par0; prefetch x(2,3), x(4,5) ----
  const float* xgl = x + (size_t)(r0 + w) * DD + xj + (size_t)(lane >> 5) * BB * DD;
  {
    const float2 v = *(const float2*)xgl;
    *(unsigned*)(actb + xWb) = cvtpk2(v.x, v.y);
  }
  float2 xw = *(const float2*)(xgl + (size_t)2 * BB * DD);
  float2 xf = *(const float2*)(xgl + (size_t)4 * BB * DD);
  xgl += (size_t)6 * BB * DD;

  float c_state = 0.0f;
  __syncthreads();

  // ---- gates + elementwise (prescaled) + h write ----
  auto gates_and_h = [&](float a0, float b0, float a1, float b1, int hwp) {
    const float rcv0 = dpp_xor8(qq ? a0 : b0);
    const float rcv1 = dpp_xor8(qq ? a1 : b1);
    const float iv_ = qq ? rcv0 : a0;
    const float fv_ = qq ? b0 : rcv0;
    const float gv_ = qq ? rcv1 : a1;
    const float ov_ = qq ? b1 : rcv1;
    const float iv = RCPF(1.0f + EXP2F(iv_));
    const float fv = RCPF(1.0f + EXP2F(fv_));
    const float gv = fmaf(-2.0f, RCPF(1.0f + EXP2F(gv_)), 1.0f);
    const float ov = RCPF(1.0f + EXP2F(ov_));
    c_state = fmaf(fv, c_state, iv * gv);
    const float tc = fmaf(-2.0f, RCPF(1.0f + EXP2F(GS_G * c_state)), 1.0f);
    *(unsigned short*)(actb + hWb + hwp) = bfu(ov * tc);
  };

  // ---- one iteration = stepA (t, h par0->par1) + stepB (t+1, par1->par0) ----
  // tmA/tmB/xpR are compile-time literals at every call site.
  auto iter2 = [&](int t, int tmA, int tmB, int xpR) {
    const int xpW = 128 - xpR;
    // ===== step A =====
    {
      const bf16x8 A2 = *(const bf16x8*)(actb + aoffH[0]);        // h par0
      const bf16x8 A3 = *(const bf16x8*)(actb + aoffH[1]);
      const bf16x8 X0 = *(const bf16x8*)(actb + aoffX[0] + xpR);  // x pair
      const bf16x8 X1 = *(const bf16x8*)(actb + aoffX[1] + xpR);

      // stage x pair (t+2,t+3) into other parity; rotate prefetch
      *(unsigned*)(actb + xWb + xpW) = cvtpk2(xw.x, xw.y);
      xw = xf;
      if (t + 7 < TT) xf = *(const float2*)xgl;
      xgl += (size_t)2 * BB * DD;

      // x-pass (bias folded): [0]/[2] = step t rows, [1]/[3] = step t+1
      f32x4 xCa = {biasv[0], biasv[0], biasv[0], biasv[0]};
      f32x4 xCb = {biasv[1], biasv[1], biasv[1], biasv[1]};
      xCa = MFMA16(X0, Bih[0][0], xCa); xCa = MFMA16(X1, Bih[0][1], xCa);
      xCb = MFMA16(X0, Bih[1][0], xCb); xCb = MFMA16(X1, Bih[1][1], xCb);
      f32x4 H0 = MFMA16(A2, Bhh[0][0], Z); H0 = MFMA16(A3, Bhh[0][1], H0);
      f32x4 H1 = MFMA16(A2, Bhh[1][0], Z); H1 = MFMA16(A3, Bhh[1][1], H1);

      if (w == tmA && t > 0) {
        f32x4 pacc = MFMA16(A2, pb[0], Z);
        pacc = MFMA16(A3, pb[1], pacc);
        const size_t base = ((size_t)(t - 1) * BB + r0 + 2 * lg) * AA + lr;
        out[base]      = pacc[0] + bo;
        out[base + AA] = pacc[2] + bo;
      }
      gates_and_h(H0[0] + xCa[0], H0[2] + xCa[2],
                  H1[0] + xCb[0], H1[2] + xCb[2], 128);
      block_sync_lds();

      // ===== step B (x from carried xC odd rows) =====
      const bf16x8 B2 = *(const bf16x8*)(actb + aoffH[0] + 128);  // h par1
      const bf16x8 B3 = *(const bf16x8*)(actb + aoffH[1] + 128);
      f32x4 G0 = MFMA16(B2, Bhh[0][0], Z); G0 = MFMA16(B3, Bhh[0][1], G0);
      f32x4 G1 = MFMA16(B2, Bhh[1][0], Z); G1 = MFMA16(B3, Bhh[1][1], G1);

      if (w == tmB) {
        f32x4 pacc = MFMA16(B2, pb[0], Z);
        pacc = MFMA16(B3, pb[1], pacc);
        const size_t base = ((size_t)t * BB + r0 + 2 * lg) * AA + lr;
        out[base]      = pacc[0] + bo;
        out[base + AA] = pacc[2] + bo;
      }
      gates_and_h(G0[0] + xCa[1], G0[2] + xCa[3],
                  G1[0] + xCb[1], G1[2] + xCb[3], 0);
      block_sync_lds();
    }
  };

  for (int u = 0; u < TT / 8; ++u) {
    const int t0 = u * 8;
    iter2(t0 + 0, 0, 1, 0);
    iter2(t0 + 2, 2, 3, 128);
    iter2(t0 + 4, 4, 5, 0);
    iter2(t0 + 6, 6, 7, 128);
  }

  // ---- epilogue: out[TT-1] from h(TT-1) (par0) ----
  if (w == (TT & 7)) {
    const bf16x8 A2 = *(const bf16x8*)(actb + aoffH[0]);
    const bf16x8 A3 = *(const bf16x8*)(actb + aoffH[1]);
    f32x4 pacc = MFMA16(A2, pb[0], Z);
    pacc = MFMA16(A3, pb[1], pacc);
    const size_t base = ((size_t)(TT - 1) * BB + r0 + 2 * lg) * AA + lr;
    out[base]      = pacc[0] + bo;
    out[base + AA] = pacc[2] + bo;
  }
}

extern "C" void kernel_launch(void* const* d_in, const int* in_sizes, int n_in,
                              void* d_out, int out_size, void* d_ws, size_t ws_size,
                              hipStream_t stream) {
  const float* x     = (const float*)d_in[0];
  const float* W_ih  = (const float*)d_in[1];
  const float* W_hh  = (const float*)d_in[2];
  const float* b_ih  = (const float*)d_in[3];
  const float* b_hh  = (const float*)d_in[4];
  const float* W_out = (const float*)d_in[5];
  const float* b_out = (const float*)d_in[6];
  float* out = (float*)d_out;

  lstm_actor_v14<<<dim3(BB / 8), dim3(512), 0, stream>>>(
      x, W_ih, W_hh, b_ih, b_hh, W_out, b_out, out);
}

// Round 17
// 178.825 us; speedup vs baseline: 1.5570x; 1.0103x over previous
//
#include <hip/hip_runtime.h>
#include <hip/hip_bf16.h>

// LSTM_Actor v15: v14 (181us) + X-fragments carried in registers across the
// iteration boundary (one scheduling change, zero numeric change):
//  - step B issues the ds_read of the x-pair staged in step A of the SAME
//    iteration (independent of its h reads -> hides under G-MFMAs);
//  - step A of the NEXT iteration starts its x-pass MFMAs from REGISTERS at
//    barrier-exit (no lgkm wait), fully filling the A2/A3 ds_read shadow.
// Everything else is v14 verbatim: 256 blocks x 512 thr, 8 rows/block,
// x-pair M-packing, prescaled weights, 8-step unroll, separate H/xC accs,
// DPP row_ror:8 exchange, one lgkm-only barrier per step.

#define TT 512
#define BB 2048
#define DD 64
#define AA 16
#define ROWB 512   // per A-row: x par0 128 | x par1 128 | h par0 128 | h par1 128

typedef short bf16x8 __attribute__((ext_vector_type(8)));
typedef float f32x4 __attribute__((ext_vector_type(4)));

#define MFMA16(a, b, c) __builtin_amdgcn_mfma_f32_16x16x32_bf16((a), (b), (c), 0, 0, 0)

#if defined(__has_builtin)
#  if __has_builtin(__builtin_amdgcn_exp2f)
#    define EXP2F(x) __builtin_amdgcn_exp2f(x)
#  else
#    define EXP2F(x) exp2f(x)
#  endif
#  if __has_builtin(__builtin_amdgcn_rcpf)
#    define RCPF(x) __builtin_amdgcn_rcpf(x)
#  else
#    define RCPF(x) (1.0f/(x))
#  endif
#else
#  define EXP2F(x) exp2f(x)
#  define RCPF(x) (1.0f/(x))
#endif

#define GS_I (-1.4426950408889634f)   // sigmoid pre-scale
#define GS_G (2.8853900817779268f)    // tanh pre-scale

__device__ __forceinline__ unsigned short bfu(float f) {
  union { __hip_bfloat16 b; unsigned short u; } cv;
  cv.b = __float2bfloat16(f);
  return cv.u;
}
__device__ __forceinline__ unsigned cvtpk2(float a, float b) {  // [b|a] bf16 RNE
  union { __hip_bfloat162 b2; unsigned u; } cv;
  cv.b2 = __float22bfloat162_rn(make_float2(a, b));
  return cv.u;
}
// xor-by-8 across lanes via DPP row_ror:8 (HW-validated v9-v14).
__device__ __forceinline__ float dpp_xor8(float v) {
  int i = __builtin_bit_cast(int, v);
  int r = __builtin_amdgcn_update_dpp(i, i, 0x128, 0xF, 0xF, true);
  return __builtin_bit_cast(float, r);
}
// 16B-slot swizzle within a 128B region (v10's variant; residual 2-way on
// b128 reads is structural and ~free per m136).
__device__ __forceinline__ int swz(int row, int slot) {
  return (slot ^ (row & 7) ^ ((row & 8) >> 1)) & 7;
}
// lgkm-only barrier: LDS writes visible; global loads stay in flight.
__device__ __forceinline__ void block_sync_lds() {
  __builtin_amdgcn_sched_barrier(0);
  asm volatile("s_waitcnt lgkmcnt(0)" ::: "memory");
  __builtin_amdgcn_s_barrier();
  __builtin_amdgcn_sched_barrier(0);
}

__global__ __launch_bounds__(512, 2)
void lstm_actor_v15(const float* __restrict__ x,
                    const float* __restrict__ W_ih,
                    const float* __restrict__ W_hh,
                    const float* __restrict__ b_ih,
                    const float* __restrict__ b_hh,
                    const float* __restrict__ W_out,
                    const float* __restrict__ b_out,
                    float* __restrict__ out) {
  __shared__ __align__(16) unsigned short act[16 * ROWB / 2];  // 8 KB
  char* actb = (char*)act;

  const int tid  = threadIdx.x;
  const int lane = tid & 63;
  const int w    = tid >> 6;       // wave 0..7: j-slice j0 = 8w
  const int lr   = lane & 15;
  const int lg   = lane >> 4;
  const int qq   = lr >> 3;        // 0/1: quadrant within tile pair
  const int jj   = lr & 7;
  const int r0   = blockIdx.x * 8;
  const int j0   = w * 8;

  const f32x4 Z = {0.f, 0.f, 0.f, 0.f};

  // ---- weights (bf16, PRE-SCALED): 2 packed N-tiles x 2 k-frags ----
  bf16x8 Bih[2][2], Bhh[2][2];
  float biasv[2];
#pragma unroll
  for (int nt = 0; nt < 2; ++nt) {
    const int g = (nt * 2 + qq) * 64 + j0 + jj;
    const float sc = (nt == 1 && qq == 0) ? GS_G : GS_I;
    biasv[nt] = sc * (b_ih[g] + b_hh[g]);
#pragma unroll
    for (int kt = 0; kt < 2; ++kt) {
      const float* si = W_ih + g * 64 + kt * 32 + lg * 8;
      const float* sh = W_hh + g * 64 + kt * 32 + lg * 8;
      bf16x8 vi, vh;
#pragma unroll
      for (int u = 0; u < 8; ++u) {
        vi[u] = (short)bfu(sc * si[u]);
        vh[u] = (short)bfu(sc * sh[u]);
      }
      Bih[nt][kt] = vi; Bhh[nt][kt] = vh;
    }
  }

  // ---- projection weights (unscaled, all waves) ----
  bf16x8 pb[2];
  const float bo = b_out[lr];
#pragma unroll
  for (int kt = 0; kt < 2; ++kt) {
    const float* src = W_out + lr * 64 + kt * 32 + lg * 8;
    bf16x8 vh;
#pragma unroll
    for (int u = 0; u < 8; ++u) vh[u] = (short)bfu(src[u]);
    pb[kt] = vh;
  }

  // ---- LDS geometry (v10/v14) ----
  int aoffX[2], aoffH[2];
#pragma unroll
  for (int kt = 0; kt < 2; ++kt) {
    aoffX[kt] = lr * ROWB + swz(lr, kt * 4 + lg) * 16;
    aoffH[kt] = aoffX[kt] + 256;
  }
  const int hrow = 2 * lg + qq;
  const int hj   = j0 + jj;
  const int hWb  = (2 * hrow) * ROWB + 256 + swz(2 * hrow, hj >> 3) * 16 + ((hj * 2) & 15);
  const int xrow = 2 * w + (lane >> 5);
  const int xj   = 2 * (lane & 31);
  const int xWb  = xrow * ROWB + swz(xrow, xj >> 3) * 16 + ((2 * xj) & 15);

  // ---- zero LDS (odd-row h region stays zero forever; h(-1)=0) ----
  for (int i = tid; i < 16 * ROWB / 4; i += 512) ((unsigned*)act)[i] = 0u;
  __syncthreads();

  // ---- stage x(0)/x(1) par0; prefetch x(2,3), x(4,5) ----
  const float* xgl = x + (size_t)(r0 + w) * DD + xj + (size_t)(lane >> 5) * BB * DD;
  {
    const float2 v = *(const float2*)xgl;
    *(unsigned*)(actb + xWb) = cvtpk2(v.x, v.y);
  }
  float2 xw = *(const float2*)(xgl + (size_t)2 * BB * DD);
  float2 xf = *(const float2*)(xgl + (size_t)4 * BB * DD);
  xgl += (size_t)6 * BB * DD;

  float c_state = 0.0f;
  __syncthreads();

  // ---- X fragments for iteration 0, read once here (par0) ----
  bf16x8 XA0 = *(const bf16x8*)(actb + aoffX[0]);
  bf16x8 XA1 = *(const bf16x8*)(actb + aoffX[1]);

  // ---- gates + elementwise (prescaled) + h write ----
  auto gates_and_h = [&](float a0, float b0, float a1, float b1, int hwp) {
    const float rcv0 = dpp_xor8(qq ? a0 : b0);
    const float rcv1 = dpp_xor8(qq ? a1 : b1);
    const float iv_ = qq ? rcv0 : a0;
    const float fv_ = qq ? b0 : rcv0;
    const float gv_ = qq ? rcv1 : a1;
    const float ov_ = qq ? b1 : rcv1;
    const float iv = RCPF(1.0f + EXP2F(iv_));
    const float fv = RCPF(1.0f + EXP2F(fv_));
    const float gv = fmaf(-2.0f, RCPF(1.0f + EXP2F(gv_)), 1.0f);
    const float ov = RCPF(1.0f + EXP2F(ov_));
    c_state = fmaf(fv, c_state, iv * gv);
    const float tc = fmaf(-2.0f, RCPF(1.0f + EXP2F(GS_G * c_state)), 1.0f);
    *(unsigned short*)(actb + hWb + hwp) = bfu(ov * tc);
  };

  // ---- one iteration = stepA (t, par0->par1) + stepB (t+1, par1->par0) ----
  // XA0/XA1 hold this iteration's x-pair IN REGISTERS at entry; step B
  // refills them for the next iteration from the pair staged in step A.
  auto iter2 = [&](int t, int tmA, int tmB, int xpR) {
    const int xpW = 128 - xpR;
    // ===== step A: x-MFMAs from regs fill the A2/A3 ds_read shadow =====
    {
      const bf16x8 A2 = *(const bf16x8*)(actb + aoffH[0]);        // h par0
      const bf16x8 A3 = *(const bf16x8*)(actb + aoffH[1]);

      f32x4 xCa = {biasv[0], biasv[0], biasv[0], biasv[0]};
      f32x4 xCb = {biasv[1], biasv[1], biasv[1], biasv[1]};
      xCa = MFMA16(XA0, Bih[0][0], xCa); xCa = MFMA16(XA1, Bih[0][1], xCa);
      xCb = MFMA16(XA0, Bih[1][0], xCb); xCb = MFMA16(XA1, Bih[1][1], xCb);

      // stage x pair (t+2,t+3) into other parity; rotate prefetch
      *(unsigned*)(actb + xWb + xpW) = cvtpk2(xw.x, xw.y);
      xw = xf;
      if (t + 7 < TT) xf = *(const float2*)xgl;
      xgl += (size_t)2 * BB * DD;

      f32x4 H0 = MFMA16(A2, Bhh[0][0], Z); H0 = MFMA16(A3, Bhh[0][1], H0);
      f32x4 H1 = MFMA16(A2, Bhh[1][0], Z); H1 = MFMA16(A3, Bhh[1][1], H1);

      if (w == tmA && t > 0) {
        f32x4 pacc = MFMA16(A2, pb[0], Z);
        pacc = MFMA16(A3, pb[1], pacc);
        const size_t base = ((size_t)(t - 1) * BB + r0 + 2 * lg) * AA + lr;
        out[base]      = pacc[0] + bo;
        out[base + AA] = pacc[2] + bo;
      }
      gates_and_h(H0[0] + xCa[0], H0[2] + xCa[2],
                  H1[0] + xCb[0], H1[2] + xCb[2], 128);
      block_sync_lds();

      // ===== step B: h reads + NEXT iteration's X reads (independent) =====
      const bf16x8 B2 = *(const bf16x8*)(actb + aoffH[0] + 128);  // h par1
      const bf16x8 B3 = *(const bf16x8*)(actb + aoffH[1] + 128);
      // refill X regs for iter it+1 from the pair staged above (parity xpW);
      // latency hides under the G-MFMAs below.
      XA0 = *(const bf16x8*)(actb + aoffX[0] + xpW);
      XA1 = *(const bf16x8*)(actb + aoffX[1] + xpW);

      f32x4 G0 = MFMA16(B2, Bhh[0][0], Z); G0 = MFMA16(B3, Bhh[0][1], G0);
      f32x4 G1 = MFMA16(B2, Bhh[1][0], Z); G1 = MFMA16(B3, Bhh[1][1], G1);

      if (w == tmB) {
        f32x4 pacc = MFMA16(B2, pb[0], Z);
        pacc = MFMA16(B3, pb[1], pacc);
        const size_t base = ((size_t)t * BB + r0 + 2 * lg) * AA + lr;
        out[base]      = pacc[0] + bo;
        out[base + AA] = pacc[2] + bo;
      }
      gates_and_h(G0[0] + xCa[1], G0[2] + xCa[3],
                  G1[0] + xCb[1], G1[2] + xCb[3], 0);
      block_sync_lds();
    }
  };

  for (int u = 0; u < TT / 8; ++u) {
    const int t0 = u * 8;
    iter2(t0 + 0, 0, 1, 0);
    iter2(t0 + 2, 2, 3, 128);
    iter2(t0 + 4, 4, 5, 0);
    iter2(t0 + 6, 6, 7, 128);
  }

  // ---- epilogue: out[TT-1] from h(TT-1) (par0) ----
  if (w == (TT & 7)) {
    const bf16x8 A2 = *(const bf16x8*)(actb + aoffH[0]);
    const bf16x8 A3 = *(const bf16x8*)(actb + aoffH[1]);
    f32x4 pacc = MFMA16(A2, pb[0], Z);
    pacc = MFMA16(A3, pb[1], pacc);
    const size_t base = ((size_t)(TT - 1) * BB + r0 + 2 * lg) * AA + lr;
    out[base]      = pacc[0] + bo;
    out[base + AA] = pacc[2] + bo;
  }
}

extern "C" void kernel_launch(void* const* d_in, const int* in_sizes, int n_in,
                              void* d_out, int out_size, void* d_ws, size_t ws_size,
                              hipStream_t stream) {
  const float* x     = (const float*)d_in[0];
  const float* W_ih  = (const float*)d_in[1];
  const float* W_hh  = (const float*)d_in[2];
  const float* b_ih  = (const float*)d_in[3];
  const float* b_hh  = (const float*)d_in[4];
  const float* W_out = (const float*)d_in[5];
  const float* b_out = (const float*)d_in[6];
  float* out = (float*)d_out;

  lstm_actor_v15<<<dim3(BB / 8), dim3(512), 0, stream>>>(
      x, W_ih, W_hh, b_ih, b_hh, W_out, b_out, out);
}